// Round 2
// baseline (5631.193 us; speedup 1.0000x reference)
//
#include <hip/hip_runtime.h>
#include <math.h>

#define NTHR   512
#define SWEEPS 7

// Ring movement (round-robin / Brent-Luk): content of slot s moves to next(s).
// slot 0 fixed; even s -> s+2 (62 -> 63); odd s -> s-2 (1 -> 2).
__device__ __forceinline__ int ring_next_even(int s) {   // s even
    return (s == 0) ? 0 : ((s == 62) ? 63 : s + 2);
}
__device__ __forceinline__ int ring_next_odd(int s) {    // s odd
    return (s == 1) ? 2 : s - 2;
}
// Split-parity column position: even cols -> 0..31, odd cols -> 32..63.
__device__ __forceinline__ int cpos(int c) {
    return (c >> 1) + ((c & 1) << 5);
}

// A layout: row-pair-interleaved float2.
//   element (r, c) at  A[(r>>1)*128 + cpos(c)*2 + (r&1)]
// -> the 2x2 Jacobi block (rows 2I,2I+1 x cols 2J,2J+1) is TWO ds_read_b64:
//      (m00,m10) at [I*128 + 2J],  (m01,m11) at [I*128 + 2J + 64]
// Reads: stride-8B dense (conflict-free). Writes: destination rows scatter
// into different pairs (ring property), stay 8 scalar b32 at stride-2-float
// (2-way aliasing = free). Cuts A-side LDS instructions 128 -> 96 per
// block-round wave-instr count: total 196 -> ~164.
__global__ __launch_bounds__(NTHR, 8)
void logeig_jacobi(const float* __restrict__ x, float* __restrict__ out) {
    __shared__ __align__(16) float A[64 * 64];
    __shared__ __align__(16) float Vt[64 * 64];   // plain row-major
    __shared__ __align__(16) float2 prm[32];
    __shared__ float logw[64];

    const int tid = threadIdx.x;
    const int w   = tid >> 6;              // wave id 0..7
    const int lan = tid & 63;
    const int J   = tid & 31;              // column-pair id
    const int bit = (lan >> 5) & 1;
    const int base = 4 * w + bit;          // row-pair I = base + 2k, k<2
    const int kv  = tid >> 4;              // Vt row-pair id 0..31
    const int cch = tid & 15;              // Vt float4 chunk

    // thread-constant write column float-offsets (pos*2) after ring move
    const int w2P = 2 * cpos(ring_next_even(2 * J));
    const int w2Q = 2 * cpos(ring_next_odd(2 * J + 1));
    // thread-constant destination row offsets for the 2 blocks
    int oP[2], oQ[2];
    #pragma unroll
    for (int k = 0; k < 2; ++k) {
        int I  = base + 2 * k;
        int dP = ring_next_even(2 * I);
        int dQ = ring_next_odd(2 * I + 1);
        oP[k] = (dP >> 1) * 128 + (dP & 1);
        oQ[k] = (dQ >> 1) * 128 + (dQ & 1);
    }
    // Vt destination rows
    const int vdP = ring_next_even(2 * kv);
    const int vdQ = ring_next_odd(2 * kv + 1);

    const size_t base_el = (size_t)blockIdx.x * 4096;

    // ---- load A into row-pair float2 layout, Vt = I ----
    {
        const float4* x4 = (const float4*)(x + base_el);
        for (int idx4 = tid; idx4 < 1024; idx4 += NTHR) {
            int i = idx4 >> 4, t = idx4 & 15;      // row i, cols 4t..4t+3
            float4 v = x4[idx4];
            int pb = (i >> 1) * 128 + (i & 1);
            // col 4t   -> pos 2t    -> off 4t
            // col 4t+1 -> pos 2t+32 -> off 4t+64
            // col 4t+2 -> pos 2t+1  -> off 4t+2
            // col 4t+3 -> pos 2t+33 -> off 4t+66
            A[pb + 4 * t]          = v.x;
            A[pb + 4 * t + 64]     = v.y;
            A[pb + 4 * t + 2]      = v.z;
            A[pb + 4 * t + 66]     = v.w;
            float4 id;
            id.x = (4 * t + 0 == i) ? 1.0f : 0.0f;
            id.y = (4 * t + 1 == i) ? 1.0f : 0.0f;
            id.z = (4 * t + 2 == i) ? 1.0f : 0.0f;
            id.w = (4 * t + 3 == i) ? 1.0f : 0.0f;
            ((float4*)Vt)[idx4] = id;
        }
    }
    __syncthreads();

    for (int sweep = 0; sweep < SWEEPS; ++sweep) {
        for (int r = 0; r < 63; ++r) {
            // ---- rotation params for the 32 adjacent slot pairs ----
            if (tid < 32) {
                int k = tid;
                // (app, apq) via symmetry, (apq, aqq) directly: 2 x b64
                float2 lo = *(const float2*)&A[k * 128 + 2 * k];       // (a_pp, a_qp)
                float2 hi = *(const float2*)&A[k * 128 + 2 * k + 64];  // (a_pq, a_qq)
                float app = lo.x, apq = hi.x, aqq = hi.y;
                float c = 1.0f, s = 0.0f;
                if (apq != 0.0f) {
                    float tau = (aqq - app) / (2.0f * apq);
                    float t   = copysignf(1.0f, tau) /
                                (fabsf(tau) + sqrtf(1.0f + tau * tau));
                    c = 1.0f / sqrtf(1.0f + t * t);
                    s = t * c;
                }
                prm[k] = make_float2(c, s);
            }

            // ---- read old A 2x2 blocks (2 x ds_read_b64 each) and Vt ----
            float4 ablk[2];
            #pragma unroll
            for (int k = 0; k < 2; ++k) {
                int I = base + 2 * k;
                float2 lo = *(const float2*)&A[I * 128 + 2 * J];        // (m00, m10)
                float2 hi = *(const float2*)&A[I * 128 + 2 * J + 64];   // (m01, m11)
                ablk[k] = make_float4(lo.x, hi.x, lo.y, hi.y);
            }
            // Vt: one row-pair per thread (16-lane contiguous float4 groups)
            float4 vtop = *(const float4*)&Vt[(2 * kv) * 64 + 4 * cch];
            float4 vbot = *(const float4*)&Vt[(2 * kv + 1) * 64 + 4 * cch];
            __syncthreads();   // B1: all reads done; prm visible

            float2 pJ = prm[J];
            float2 pV = prm[kv];           // 16-lane broadcast
            float2 pI[2];
            pI[0] = prm[base];
            pI[1] = prm[base + 2];

            // ---- rotate 2x2 blocks, write to ring-moved positions ----
            #pragma unroll
            for (int k = 0; k < 2; ++k) {
                float cI = pI[k].x, sI = pI[k].y;
                float cJ = pJ.x,   sJ = pJ.y;
                float m00 = ablk[k].x, m01 = ablk[k].y;
                float m10 = ablk[k].z, m11 = ablk[k].w;
                float t00 = cI * m00 - sI * m10, t01 = cI * m01 - sI * m11;
                float t10 = sI * m00 + cI * m10, t11 = sI * m01 + cI * m11;
                float n00 = cJ * t00 - sJ * t01, n01 = sJ * t00 + cJ * t01;
                float n10 = cJ * t10 - sJ * t11, n11 = sJ * t10 + cJ * t11;
                A[oP[k] + w2P] = n00;
                A[oP[k] + w2Q] = n01;
                A[oQ[k] + w2P] = n10;
                A[oQ[k] + w2Q] = n11;
            }

            // ---- rotate Vt row-pair, write to ring-moved rows ----
            {
                float cV = pV.x, sV = pV.y;
                float4 n0, n1;
                n0.x = cV * vtop.x - sV * vbot.x;  n1.x = sV * vtop.x + cV * vbot.x;
                n0.y = cV * vtop.y - sV * vbot.y;  n1.y = sV * vtop.y + cV * vbot.y;
                n0.z = cV * vtop.z - sV * vbot.z;  n1.z = sV * vtop.z + cV * vbot.z;
                n0.w = cV * vtop.w - sV * vbot.w;  n1.w = sV * vtop.w + cV * vbot.w;
                *(float4*)&Vt[vdP * 64 + 4 * cch] = n0;
                *(float4*)&Vt[vdQ * 64 + 4 * cch] = n1;
            }
            __syncthreads();   // B2: writes done -> next round
        }
    }

    // ---- epilogue: out = Vt^T diag(log diag A) Vt ----
    if (tid < 64) {
        int p = cpos(tid);
        logw[tid] = logf(A[(tid >> 1) * 128 + 2 * p + (tid & 1)]);
    }
    __syncthreads();

    // W[s][*] = Vt[s][*] * logw[s]  -> reuse A (plain layout now)
    for (int idx4 = tid; idx4 < 1024; idx4 += NTHR) {
        int k = idx4 >> 4;
        float lw = logw[k];
        float4 v = ((float4*)Vt)[idx4];
        v.x *= lw; v.y *= lw; v.z *= lw; v.w *= lw;
        ((float4*)A)[idx4] = v;
    }
    __syncthreads();

    // out[i][j] = sum_s W[s][i] * Vt[s][j]
    float4* out4 = (float4*)(out + base_el);
    for (int idx4 = tid; idx4 < 1024; idx4 += NTHR) {
        int i = idx4 >> 4, j4 = idx4 & 15;
        float4 acc = make_float4(0.0f, 0.0f, 0.0f, 0.0f);
        #pragma unroll 8
        for (int k = 0; k < 64; ++k) {
            float a = A[k * 64 + i];
            float4 vv = ((float4*)Vt)[k * 16 + j4];
            acc.x += a * vv.x; acc.y += a * vv.y;
            acc.z += a * vv.z; acc.w += a * vv.w;
        }
        out4[idx4] = acc;
    }
}

extern "C" void kernel_launch(void* const* d_in, const int* in_sizes, int n_in,
                              void* d_out, int out_size, void* d_ws, size_t ws_size,
                              hipStream_t stream) {
    const float* x = (const float*)d_in[0];
    float* o = (float*)d_out;
    int B = in_sizes[0] / 4096;   // 8192
    logeig_jacobi<<<B, NTHR, 0, stream>>>(x, o);
}

// Round 4
// 4599.298 us; speedup vs baseline: 1.2244x; 1.2244x over previous
//
#include <hip/hip_runtime.h>
#include <math.h>

#define NTHR   512
#define SWEEPS 7

// Ring movement (round-robin / Brent-Luk): content of slot s moves to next(s).
// slot 0 fixed; even s -> s+2 (62 -> 63); odd s -> s-2 (1 -> 2).
__device__ __forceinline__ int ring_next_even(int s) {   // s even
    return (s == 0) ? 0 : ((s == 62) ? 63 : s + 2);
}
__device__ __forceinline__ int ring_next_odd(int s) {    // s odd
    return (s == 1) ? 2 : s - 2;
}
// Split-parity column position: even cols -> 0..31, odd cols -> 32..63.
// 32 same-parity column accesses of one instr hit 32 distinct banks.
__device__ __forceinline__ int cpos(int c) {
    return (c >> 1) + ((c & 1) << 5);
}

// Symmetry-exploiting Jacobi round:
//   A is exactly symmetric every round. Each thread owns ONE unordered
//   slot-pair block {p,q} (circular diagonal d = hw+1, p = k, q = (k+d)&31;
//   d=1..15 full, d=16 half-masked -> 496 = C(32,2) blocks). It reads the
//   2x2 block once, rotates once, and writes BOTH the block and its exact
//   transpose to their ring-moved positions. Diagonal blocks are closed-form
//   (app' = app - t*apq, aqq' = aqq + t*apq, off-diag 0) written by the 32
//   param threads. Halves A-reads and rotation VALU vs the all-1024-blocks
//   version; write count unchanged; all accesses stay in the conflict-free
//   cpos permutation classes (scalar b32, 2-way max = free).
__global__ __launch_bounds__(NTHR, 8)
void logeig_jacobi(const float* __restrict__ x, float* __restrict__ out) {
    __shared__ __align__(16) float A[64 * 64];   // slot rows x split-parity cols
    __shared__ __align__(16) float Vt[64 * 64];  // plain row-major
    __shared__ __align__(16) float2 prm[32];
    __shared__ float logw[64];

    const int tid = threadIdx.x;
    const int k   = tid & 31;              // p = k
    const int hw  = tid >> 5;              // half-wave 0..15
    const int d   = hw + 1;                // circular gap 1..16
    const int q   = (k + d) & 31;
    const bool act = (d < 16) || (k < 16); // d=16: only k<16 (avoid dup pairs)

    // A read offsets (thread-constant; slots never move for the reader)
    const int ro00 = (2 * k) * 64 + q;     // (+32, +64, +96 for the rest)

    // destinations after ring move
    const int dRp = ring_next_even(2 * k);
    const int dRq = ring_next_odd(2 * k + 1);
    const int dCp = cpos(ring_next_even(2 * q));
    const int dCq = cpos(ring_next_odd(2 * q + 1));
    const int tRp = ring_next_even(2 * q);
    const int tRq = ring_next_odd(2 * q + 1);
    const int tCp = cpos(ring_next_even(2 * k));
    const int tCq = cpos(ring_next_odd(2 * k + 1));

    const int w00 = dRp * 64 + dCp, w01 = dRp * 64 + dCq;
    const int w10 = dRq * 64 + dCp, w11 = dRq * 64 + dCq;
    const int u00 = tRp * 64 + tCp, u01 = tRp * 64 + tCq;  // <- n00, n10
    const int u10 = tRq * 64 + tCp, u11 = tRq * 64 + tCq;  // <- n01, n11
    // diag destinations (tid < 32 only; p = k): rows dRp/dRq, cols tCp/tCq
    const int g00 = dRp * 64 + tCp, g01 = dRp * 64 + tCq;
    const int g10 = dRq * 64 + tCp, g11 = dRq * 64 + tCq;

    // Vt indices (unchanged from the 512-thread version)
    const int kv  = tid >> 4;              // Vt row-pair id 0..31
    const int cch = tid & 15;              // float4 chunk
    const int vdP = ring_next_even(2 * kv);
    const int vdQ = ring_next_odd(2 * kv + 1);

    const size_t base_el = (size_t)blockIdx.x * 4096;

    // ---- load A into split-parity layout (float4 -> two float2), Vt = I ----
    {
        const float4* x4 = (const float4*)(x + base_el);
        for (int idx4 = tid; idx4 < 1024; idx4 += NTHR) {
            int i = idx4 >> 4, t = idx4 & 15;      // cols 4t..4t+3
            float4 v = x4[idx4];
            *(float2*)&A[i * 64 + 2 * t]      = make_float2(v.x, v.z);
            *(float2*)&A[i * 64 + 32 + 2 * t] = make_float2(v.y, v.w);
            float4 id;
            id.x = (4 * t + 0 == i) ? 1.0f : 0.0f;
            id.y = (4 * t + 1 == i) ? 1.0f : 0.0f;
            id.z = (4 * t + 2 == i) ? 1.0f : 0.0f;
            id.w = (4 * t + 3 == i) ? 1.0f : 0.0f;
            ((float4*)Vt)[idx4] = id;
        }
    }
    __syncthreads();

    for (int sweep = 0; sweep < SWEEPS; ++sweep) {
        for (int r = 0; r < 63; ++r) {
            // ---- rotation params for the 32 adjacent slot pairs ----
            float app = 0.0f, apq = 0.0f, aqq = 0.0f, tpar = 0.0f;
            if (tid < 32) {
                app = A[(2 * k) * 64 + k];            // pos(2k)   = k
                apq = A[(2 * k) * 64 + 32 + k];       // pos(2k+1) = 32+k
                aqq = A[(2 * k + 1) * 64 + 32 + k];
                float c = 1.0f, s = 0.0f;
                if (apq != 0.0f) {
                    float tau = (aqq - app) / (2.0f * apq);
                    tpar = copysignf(1.0f, tau) /
                           (fabsf(tau) + sqrtf(1.0f + tau * tau));
                    c = 1.0f / sqrtf(1.0f + tpar * tpar);
                    s = tpar * c;
                }
                prm[k] = make_float2(c, s);
            }

            // ---- read my 2x2 block (conflict-free b32) and Vt row-pair ----
            float m00 = 0.f, m01 = 0.f, m10 = 0.f, m11 = 0.f;
            if (act) {
                m00 = A[ro00];       m01 = A[ro00 + 32];
                m10 = A[ro00 + 64];  m11 = A[ro00 + 96];
            }
            float4 vtop = *(const float4*)&Vt[(2 * kv) * 64 + 4 * cch];
            float4 vbot = *(const float4*)&Vt[(2 * kv + 1) * 64 + 4 * cch];
            __syncthreads();   // B1: all reads done; prm visible

            float2 pV = prm[kv];           // 16-lane broadcast

            // ---- rotate block, write it + its transpose (ring-moved) ----
            if (act) {
                float2 pP = prm[k];
                float2 pQ = prm[q];
                float cP = pP.x, sP = pP.y, cQ = pQ.x, sQ = pQ.y;
                float t00 = cP * m00 - sP * m10, t01 = cP * m01 - sP * m11;
                float t10 = sP * m00 + cP * m10, t11 = sP * m01 + cP * m11;
                float n00 = cQ * t00 - sQ * t01, n01 = sQ * t00 + cQ * t01;
                float n10 = cQ * t10 - sQ * t11, n11 = sQ * t10 + cQ * t11;
                A[w00] = n00;  A[w01] = n01;
                A[w10] = n10;  A[w11] = n11;
                A[u00] = n00;  A[u01] = n10;   // transpose block
                A[u10] = n01;  A[u11] = n11;
            }
            // diagonal block: closed form, zero off-diagonals
            if (tid < 32) {
                A[g00] = app - tpar * apq;
                A[g01] = 0.0f;
                A[g10] = 0.0f;
                A[g11] = aqq + tpar * apq;
            }

            // ---- rotate Vt row-pair, write to ring-moved rows ----
            {
                float cV = pV.x, sV = pV.y;
                float4 n0, n1;
                n0.x = cV * vtop.x - sV * vbot.x;  n1.x = sV * vtop.x + cV * vbot.x;
                n0.y = cV * vtop.y - sV * vbot.y;  n1.y = sV * vtop.y + cV * vbot.y;
                n0.z = cV * vtop.z - sV * vbot.z;  n1.z = sV * vtop.z + cV * vbot.z;
                n0.w = cV * vtop.w - sV * vbot.w;  n1.w = sV * vtop.w + cV * vbot.w;
                *(float4*)&Vt[vdP * 64 + 4 * cch] = n0;
                *(float4*)&Vt[vdQ * 64 + 4 * cch] = n1;
            }
            __syncthreads();   // B2: writes done -> next round
        }
    }

    // ---- epilogue: out = Vt^T diag(log diag A) Vt ----
    if (tid < 64) {
        int p = (tid >> 1) + ((tid & 1) << 5);   // cpos(tid)
        logw[tid] = logf(A[tid * 64 + p]);
    }
    __syncthreads();

    // W[s][*] = Vt[s][*] * logw[s]  -> reuse A (plain layout now)
    for (int idx4 = tid; idx4 < 1024; idx4 += NTHR) {
        int kk = idx4 >> 4;
        float lw = logw[kk];
        float4 v = ((float4*)Vt)[idx4];
        v.x *= lw; v.y *= lw; v.z *= lw; v.w *= lw;
        ((float4*)A)[idx4] = v;
    }
    __syncthreads();

    // out[i][j] = sum_s W[s][i] * Vt[s][j]
    float4* out4 = (float4*)(out + base_el);
    for (int idx4 = tid; idx4 < 1024; idx4 += NTHR) {
        int i = idx4 >> 4, j4 = idx4 & 15;
        float4 acc = make_float4(0.0f, 0.0f, 0.0f, 0.0f);
        #pragma unroll 8
        for (int kk = 0; kk < 64; ++kk) {
            float a = A[kk * 64 + i];
            float4 vv = ((float4*)Vt)[kk * 16 + j4];
            acc.x += a * vv.x; acc.y += a * vv.y;
            acc.z += a * vv.z; acc.w += a * vv.w;
        }
        out4[idx4] = acc;
    }
}

extern "C" void kernel_launch(void* const* d_in, const int* in_sizes, int n_in,
                              void* d_out, int out_size, void* d_ws, size_t ws_size,
                              hipStream_t stream) {
    const float* x = (const float*)d_in[0];
    float* o = (float*)d_out;
    int B = in_sizes[0] / 4096;   // 8192
    logeig_jacobi<<<B, NTHR, 0, stream>>>(x, o);
}